// Round 7
// baseline (52406.134 us; speedup 1.0000x reference)
//
#include <hip/hip_runtime.h>

// ---------------------------------------------------------------------------
// TransitionDown: FPS (M=N/4) -> KNN(K=16) -> Linear(64->128)+ReLU -> max-pool
// Round 7: ALGORITHMIC fps fix. Rounds 1-6 proved the register allocator will
// never keep 96+ regs of point state live (remat/spill at 64-128 VGPRs,
// ~4us/step of L2/scratch traffic). New structure: Morton counting-sort into
// 512 spatial groups of 64; per-group ball bound (c,r) prunes the min-dist
// update to the ~30-80 groups near the picked point; mind lives in global
// (L2-hot), per-group (max,argmax-orig-idx) packed u64 in LDS. Exact: bound
// is conservative (margins cover fp rounding), argmax tie-breaks on ORIGINAL
// index so sort order / atomic scatter nondeterminism cannot change results.
// ---------------------------------------------------------------------------

#define FPS_T   1024
#define NG      512          // N/64 groups
#define NCELL   4096         // 16x16x16 Morton cells
#define KNN_K   16
#define MLP_ROWS 32

__device__ __forceinline__ int cell_key(float x, float y, float z)
{
    // quantize each coord to 4 bits over [-6,6], Morton-interleave -> 12 bits
    int qx = (int)((x + 6.0f) * 1.3333333f);
    int qy = (int)((y + 6.0f) * 1.3333333f);
    int qz = (int)((z + 6.0f) * 1.3333333f);
    qx = qx < 0 ? 0 : (qx > 15 ? 15 : qx);
    qy = qy < 0 ? 0 : (qy > 15 ? 15 : qy);
    qz = qz < 0 ? 0 : (qz > 15 ? 15 : qz);
    // spread bits 0,1,2,3 -> 0,3,6,9
    auto spread = [](int v) {
        return (v & 1) | ((v & 2) << 2) | ((v & 4) << 4) | ((v & 8) << 6);
    };
    return spread(qx) | (spread(qy) << 1) | (spread(qz) << 2);
}

// --- SoA transpose of pos (for KNN) ----------------------------------------
__global__ void prep_kernel(const float* __restrict__ pos, float* __restrict__ posx,
                            float* __restrict__ posy, float* __restrict__ posz, int N)
{
    const int i = blockIdx.x * blockDim.x + threadIdx.x;
    if (i < N) {
        posx[i] = pos[3 * i + 0];
        posy[i] = pos[3 * i + 1];
        posz[i] = pos[3 * i + 2];
    }
}

// --- counting sort by Morton cell ------------------------------------------
__global__ void zero_kernel(int* __restrict__ hist)
{
    hist[blockIdx.x * blockDim.x + threadIdx.x] = 0;
}

__global__ void hist_kernel(const float* __restrict__ pos, int* __restrict__ hist, int N)
{
    const int i = blockIdx.x * blockDim.x + threadIdx.x;
    if (i < N)
        atomicAdd(&hist[cell_key(pos[3 * i], pos[3 * i + 1], pos[3 * i + 2])], 1);
}

__global__ __launch_bounds__(1024) void scan_kernel(int* __restrict__ hist)
{
    __shared__ int part[1024];
    const int t = threadIdx.x;
    const int v0 = hist[t * 4 + 0], v1 = hist[t * 4 + 1];
    const int v2 = hist[t * 4 + 2], v3 = hist[t * 4 + 3];
    const int tot = v0 + v1 + v2 + v3;
    int acc = tot;
    part[t] = acc;
    __syncthreads();
    for (int off = 1; off < 1024; off <<= 1) {
        const int add = (t >= off) ? part[t - off] : 0;
        __syncthreads();
        acc += add;
        part[t] = acc;
        __syncthreads();
    }
    const int ex = acc - tot;               // exclusive prefix
    hist[t * 4 + 0] = ex;
    hist[t * 4 + 1] = ex + v0;
    hist[t * 4 + 2] = ex + v0 + v1;
    hist[t * 4 + 3] = ex + v0 + v1 + v2;
}

__global__ void scatter_kernel(const float* __restrict__ pos, int* __restrict__ cellptr,
                               float4* __restrict__ spts, float* __restrict__ mind, int N)
{
    const int i = blockIdx.x * blockDim.x + threadIdx.x;
    if (i < N) {
        const float x = pos[3 * i], y = pos[3 * i + 1], z = pos[3 * i + 2];
        const int dst = atomicAdd(&cellptr[cell_key(x, y, z)], 1);
        spts[dst] = make_float4(x, y, z, __int_as_float(i));   // .w = original index
        mind[dst] = __builtin_inff();                          // ws is re-poisoned: init here
    }
}

// --- per-group ball: centroid + conservative radius ------------------------
__global__ __launch_bounds__(256) void grpmeta_kernel(const float4* __restrict__ spts,
                                                      float4* __restrict__ grp, int ngroups)
{
    const int g = (int)((blockIdx.x * (unsigned)blockDim.x + threadIdx.x) >> 6);
    const int lane = threadIdx.x & 63;
    if (g >= ngroups) return;
    const float4 p = spts[(g << 6) + lane];
    float sx = p.x, sy = p.y, sz = p.z;
#pragma unroll
    for (int off = 32; off; off >>= 1) {
        sx += __shfl_xor(sx, off);
        sy += __shfl_xor(sy, off);
        sz += __shfl_xor(sz, off);
    }
    const float cx = sx * (1.0f / 64.0f), cy = sy * (1.0f / 64.0f), cz = sz * (1.0f / 64.0f);
    const float dx = p.x - cx, dy = p.y - cy, dz = p.z - cz;
    float d2 = dx * dx + dy * dy + dz * dz;
#pragma unroll
    for (int off = 32; off; off >>= 1) d2 = fmaxf(d2, __shfl_xor(d2, off));
    if (lane == 0)
        grp[g] = make_float4(cx, cy, cz, sqrtf(d2) * 1.0005f + 1e-6f);  // inflated: conservative
}

// --- h = relu(x @ W + b), x[N,64], W[64,128], h[N,128] ----------------------
__global__ __launch_bounds__(256) void mlp_kernel(
    const float* __restrict__ x, const float* __restrict__ W,
    const float* __restrict__ b, float* __restrict__ h, int N)
{
    __shared__ float ws[64 * 128];
    __shared__ float xs[MLP_ROWS * 65];
    const int t = threadIdx.x;
    const int r0 = blockIdx.x * MLP_ROWS;

    for (int i = t; i < 64 * 128; i += 256) ws[i] = W[i];
    for (int i = t; i < MLP_ROWS * 64; i += 256) {
        const int r = i >> 6, k = i & 63;
        xs[r * 65 + k] = x[r0 * 64 + i];
    }
    __syncthreads();

    const int tx = t & 31, ty = t >> 5;
    const int c0 = tx * 4, rr = ty * 4;
    float acc[4][4];
#pragma unroll
    for (int i = 0; i < 4; ++i)
#pragma unroll
        for (int j = 0; j < 4; ++j) acc[i][j] = 0.0f;

    for (int k = 0; k < 64; ++k) {
        const float4 w4 = *(const float4*)(&ws[k * 128 + c0]);
#pragma unroll
        for (int i = 0; i < 4; ++i) {
            const float xv = xs[(rr + i) * 65 + k];
            acc[i][0] += xv * w4.x;
            acc[i][1] += xv * w4.y;
            acc[i][2] += xv * w4.z;
            acc[i][3] += xv * w4.w;
        }
    }
    const float4 b4 = *(const float4*)(&b[c0]);
#pragma unroll
    for (int i = 0; i < 4; ++i) {
        float4 o;
        o.x = fmaxf(acc[i][0] + b4.x, 0.0f);
        o.y = fmaxf(acc[i][1] + b4.y, 0.0f);
        o.z = fmaxf(acc[i][2] + b4.z, 0.0f);
        o.w = fmaxf(acc[i][3] + b4.w, 0.0f);
        *(float4*)(&h[(size_t)(r0 + rr + i) * 128 + c0]) = o;
    }
}

// --- FPS with group-ball pruning (exact) ------------------------------------
// Per-group LDS key: (float_bits(maxmind) << 32) | (0xffffffff - orig_idx).
// u64 max == (max mind, tie -> lowest ORIGINAL index) == jnp.argmax semantics.
__global__ __launch_bounds__(FPS_T) void fps2_kernel(
    const float4* __restrict__ spts, float* __restrict__ mind,
    const float4* __restrict__ grp, const float* __restrict__ pos,
    int* __restrict__ out_idx, int M)
{
    const int t = threadIdx.x;
    const int w = t >> 6;
    const int lane = t & 63;

    __shared__ unsigned long long gkey[NG];
    __shared__ int pickSh;

    for (int i = t; i < NG; i += FPS_T)
        gkey[i] = (0x7f800000ULL << 32);          // maxmind = +inf -> all touched at s=1
    if (t == 0) { out_idx[0] = 0; pickSh = 0; }
    __syncthreads();

    for (int s = 1; s < M; ++s) {
        const int po = __builtin_amdgcn_readfirstlane(pickSh);   // original index, uniform
        const float lx = pos[3 * po + 0];
        const float ly = pos[3 * po + 1];
        const float lz = pos[3 * po + 2];

        // bound check: lanes 0..31 evaluate this wave's 32 groups
        bool touched = false;
        if (lane < 32) {
            const int g = (w << 5) + lane;
            const float4 m4 = grp[g];
            const float ddx = lx - m4.x, ddy = ly - m4.y, ddz = lz - m4.z;
            const float dc = sqrtf(ddx * ddx + ddy * ddy + ddz * ddz);
            const float lb = dc - m4.w;
            const float gm = __uint_as_float((unsigned)(gkey[g] >> 32));
            touched = (lb <= 0.0f) || (lb * lb * 0.9995f < gm);   // margin: conservative skip
        }
        unsigned long long mask = __ballot(touched);

        while (mask) {
            const int k = __builtin_ctzll(mask);
            mask &= mask - 1;
            const int g = (w << 5) + k;
            const int base = (g << 6) + lane;
            const float4 p = spts[base];
            float md = mind[base];
            const float dx = p.x - lx;
            const float dy = p.y - ly;
            const float dz = p.z - lz;
            const float d = dx * dx + dy * dy + dz * dz;   // token-identical to rounds 1-6
            md = fminf(md, d);
            mind[base] = md;
            const unsigned oi = (unsigned)__float_as_int(p.w);
            unsigned long long key =
                ((unsigned long long)__float_as_uint(md) << 32) | (0xffffffffu - oi);
#pragma unroll
            for (int off = 32; off; off >>= 1) {
                const unsigned long long o = __shfl_xor(key, off);
                if (o > key) key = o;
            }
            if (lane == 0) gkey[g] = key;
        }
        __syncthreads();                                   // all gkey updates visible

        if (w == 0) {
            unsigned long long best = 0;
#pragma unroll
            for (int j = 0; j < NG / 64; ++j) {
                const unsigned long long v = gkey[lane + (j << 6)];
                if (v > best) best = v;
            }
#pragma unroll
            for (int off = 32; off; off >>= 1) {
                const unsigned long long o = __shfl_xor(best, off);
                if (o > best) best = o;
            }
            if (lane == 0) {
                const int pick = (int)(0xffffffffu - (unsigned)(best & 0xffffffffu));
                out_idx[s] = pick;
                pickSh = pick;
            }
        }
        __syncthreads();                                   // pickSh ready; gkey safe to rewrite
    }
}

// --- KNN (exact top-16 by (d, idx)) + gather-max over h + sub outputs -------
__global__ __launch_bounds__(256) void knn_kernel(
    const float* __restrict__ posx, const float* __restrict__ posy,
    const float* __restrict__ posz, const int* __restrict__ idx,
    const float* __restrict__ h, const float* __restrict__ pos,
    const int* __restrict__ batch, float* __restrict__ out,
    float* __restrict__ out_subpos, int* __restrict__ out_subbatch,
    int N, int M, int Cout)
{
    const int q = (int)((blockIdx.x * (unsigned)blockDim.x + threadIdx.x) >> 6);
    const int lane = threadIdx.x & 63;
    if (q >= M) return;

    const int qi = idx[q];
    const float qx = posx[qi], qy = posy[qi], qz = posz[qi];

    float d16[KNN_K]; int i16[KNN_K];
#pragma unroll
    for (int k = 0; k < KNN_K; ++k) { d16[k] = __builtin_inff(); i16[k] = 0x7fffffff; }
    float lmax = __builtin_inff();
    int lslot = 0;
    float T = __builtin_inff();

    const int iters = N >> 6;
    for (int c = 0; c < iters; ++c) {
        const int p = c * 64 + lane;
        const float dx = posx[p] - qx;
        const float dy = posy[p] - qy;
        const float dz = posz[p] - qz;
        const float d = dx * dx + dy * dy + dz * dz;
        if (d < T && d < lmax) {
            d16[lslot] = d; i16[lslot] = p;
            lmax = d16[0]; lslot = 0;
#pragma unroll
            for (int k = 1; k < KNN_K; ++k)
                if (d16[k] > lmax) { lmax = d16[k]; lslot = k; }
        }
        if ((c & 31) == 31) {
            float tt = lmax;
#pragma unroll
            for (int off = 32; off > 0; off >>= 1)
                tt = fminf(tt, __shfl_xor(tt, off));
            T = tt;
        }
    }

    int nbr[KNN_K];
#pragma unroll
    for (int r = 0; r < KNN_K; ++r) {
        float lv = d16[0]; int ls = 0;
#pragma unroll
        for (int k = 1; k < KNN_K; ++k)
            if (d16[k] < lv || (d16[k] == lv && i16[k] < i16[ls])) { lv = d16[k]; ls = k; }
        float mv = lv; int mi = i16[ls];
#pragma unroll
        for (int off = 32; off > 0; off >>= 1) {
            const float ov = __shfl_xor(mv, off);
            const int   oi = __shfl_xor(mi, off);
            if (ov < mv || (ov == mv && oi < mi)) { mv = ov; mi = oi; }
        }
        if (i16[ls] == mi) d16[ls] = __builtin_inff();
        nbr[r] = mi;
    }

    for (int c = lane; c < Cout; c += 64) {
        float a = -__builtin_inff();
#pragma unroll
        for (int r = 0; r < KNN_K; ++r)
            a = fmaxf(a, h[(size_t)nbr[r] * Cout + c]);
        out[(size_t)q * Cout + c] = a;
    }
    if (lane < 3) out_subpos[q * 3 + lane] = pos[qi * 3 + lane];
    if (lane == 3) out_subbatch[q] = batch[qi];
}

// ---------------------------------------------------------------------------
extern "C" void kernel_launch(void* const* d_in, const int* in_sizes, int n_in,
                              void* d_out, int out_size, void* d_ws, size_t ws_size,
                              hipStream_t stream)
{
    const float* x     = (const float*)d_in[0];
    const float* pos   = (const float*)d_in[1];
    const int*   batch = (const int*)d_in[2];
    const float* W     = (const float*)d_in[3];
    const float* b     = (const float*)d_in[4];

    const int N    = in_sizes[2];       // 32768
    const int Cout = in_sizes[4];       // 128
    const int M    = N / 4;             // 8192
    const int ngroups = N / 64;         // 512 == NG

    // ws layout: spts f4[N] | grp f4[NG] | posx,posy,posz [N] | mind [N]
    //          | hist [NCELL] | idx [M] | h [N*Cout]
    float4* spts = (float4*)d_ws;
    float4* grp  = spts + N;
    float*  posx = (float*)(grp + NG);
    float*  posy = posx + N;
    float*  posz = posy + N;
    float*  mind = posz + N;
    int*    hist = (int*)(mind + N);
    int*    idx  = hist + NCELL;
    float*  h    = (float*)(idx + M);

    float* out          = (float*)d_out;
    float* out_subpos   = out + (size_t)M * Cout;
    int*   out_subbatch = (int*)(out_subpos + (size_t)M * 3);

    prep_kernel<<<(N + 255) / 256, 256, 0, stream>>>(pos, posx, posy, posz, N);
    zero_kernel<<<NCELL / 256, 256, 0, stream>>>(hist);
    hist_kernel<<<(N + 255) / 256, 256, 0, stream>>>(pos, hist, N);
    scan_kernel<<<1, 1024, 0, stream>>>(hist);
    scatter_kernel<<<(N + 255) / 256, 256, 0, stream>>>(pos, hist, spts, mind, N);
    grpmeta_kernel<<<(ngroups * 64 + 255) / 256, 256, 0, stream>>>(spts, grp, ngroups);
    mlp_kernel<<<N / MLP_ROWS, 256, 0, stream>>>(x, W, b, h, N);
    fps2_kernel<<<1, FPS_T, 0, stream>>>(spts, mind, grp, pos, idx, M);
    knn_kernel<<<(M * 64) / 256, 256, 0, stream>>>(posx, posy, posz, idx, h, pos, batch,
                                                   out, out_subpos, out_subbatch, N, M, Cout);
}

// Round 8
// 32118.311 us; speedup vs baseline: 1.6317x; 1.6317x over previous
//
#include <hip/hip_runtime.h>

// ---------------------------------------------------------------------------
// TransitionDown: FPS (M=N/4) -> KNN(K=16) -> Linear(64->128)+ReLU -> max-pool
// Round 8: LDS-resident FPS. Round-7 counters: VALUBusy 0.05% (pure latency),
// FETCH_SIZE ~1.2GB/dispatch in EVERY round => per-step workspace re-reads
// miss L2 and pay HBM latency. Fixes:
//   1. mind[32768] lives in LDS (128KB of the 160KB/WG pool).
//   2. group->wave ownership interleaved (g = j*16 + w): touched groups spread
//      across waves => the ~5-10 touched groups/step resolve in parallel.
//   3. per-group winner coords cached in LDS (gpt): next step's pick coords
//      come from LDS, not a global pos load => zero globals on the serial
//      chain except the touched groups' spts pulls (~1KB each, pipelined).
// Exactness: key=(bits(mind)<<32)|(0xffffffff-origIdx); u64-max == max mind,
// tie -> lowest ORIGINAL index == jnp.argmax (round-7-proven). Bound skip is
// conservative (inflated radius + 0.9995 margin).
// ---------------------------------------------------------------------------

#define FPS_T   1024
#define NW      16           // waves per block
#define GPW     32           // groups per wave
#define NG      512          // N/64 groups
#define NPTS    32768
#define NCELL   4096         // 16x16x16 Morton cells
#define KNN_K   16
#define MLP_ROWS 32

__device__ __forceinline__ int cell_key(float x, float y, float z)
{
    int qx = (int)((x + 6.0f) * 1.3333333f);
    int qy = (int)((y + 6.0f) * 1.3333333f);
    int qz = (int)((z + 6.0f) * 1.3333333f);
    qx = qx < 0 ? 0 : (qx > 15 ? 15 : qx);
    qy = qy < 0 ? 0 : (qy > 15 ? 15 : qy);
    qz = qz < 0 ? 0 : (qz > 15 ? 15 : qz);
    auto spread = [](int v) {
        return (v & 1) | ((v & 2) << 2) | ((v & 4) << 4) | ((v & 8) << 6);
    };
    return spread(qx) | (spread(qy) << 1) | (spread(qz) << 2);
}

// --- SoA transpose of pos (for KNN) ----------------------------------------
__global__ void prep_kernel(const float* __restrict__ pos, float* __restrict__ posx,
                            float* __restrict__ posy, float* __restrict__ posz, int N)
{
    const int i = blockIdx.x * blockDim.x + threadIdx.x;
    if (i < N) {
        posx[i] = pos[3 * i + 0];
        posy[i] = pos[3 * i + 1];
        posz[i] = pos[3 * i + 2];
    }
}

// --- counting sort by Morton cell ------------------------------------------
__global__ void zero_kernel(int* __restrict__ hist)
{
    hist[blockIdx.x * blockDim.x + threadIdx.x] = 0;
}

__global__ void hist_kernel(const float* __restrict__ pos, int* __restrict__ hist, int N)
{
    const int i = blockIdx.x * blockDim.x + threadIdx.x;
    if (i < N)
        atomicAdd(&hist[cell_key(pos[3 * i], pos[3 * i + 1], pos[3 * i + 2])], 1);
}

__global__ __launch_bounds__(1024) void scan_kernel(int* __restrict__ hist)
{
    __shared__ int part[1024];
    const int t = threadIdx.x;
    const int v0 = hist[t * 4 + 0], v1 = hist[t * 4 + 1];
    const int v2 = hist[t * 4 + 2], v3 = hist[t * 4 + 3];
    const int tot = v0 + v1 + v2 + v3;
    int acc = tot;
    part[t] = acc;
    __syncthreads();
    for (int off = 1; off < 1024; off <<= 1) {
        const int add = (t >= off) ? part[t - off] : 0;
        __syncthreads();
        acc += add;
        part[t] = acc;
        __syncthreads();
    }
    const int ex = acc - tot;
    hist[t * 4 + 0] = ex;
    hist[t * 4 + 1] = ex + v0;
    hist[t * 4 + 2] = ex + v0 + v1;
    hist[t * 4 + 3] = ex + v0 + v1 + v2;
}

__global__ void scatter_kernel(const float* __restrict__ pos, int* __restrict__ cellptr,
                               float4* __restrict__ spts, int N)
{
    const int i = blockIdx.x * blockDim.x + threadIdx.x;
    if (i < N) {
        const float x = pos[3 * i], y = pos[3 * i + 1], z = pos[3 * i + 2];
        const int dst = atomicAdd(&cellptr[cell_key(x, y, z)], 1);
        spts[dst] = make_float4(x, y, z, __int_as_float(i));   // .w = original index
    }
}

// --- per-group ball: centroid + conservative radius ------------------------
__global__ __launch_bounds__(256) void grpmeta_kernel(const float4* __restrict__ spts,
                                                      float4* __restrict__ grp, int ngroups)
{
    const int g = (int)((blockIdx.x * (unsigned)blockDim.x + threadIdx.x) >> 6);
    const int lane = threadIdx.x & 63;
    if (g >= ngroups) return;
    const float4 p = spts[(g << 6) + lane];
    float sx = p.x, sy = p.y, sz = p.z;
#pragma unroll
    for (int off = 32; off; off >>= 1) {
        sx += __shfl_xor(sx, off);
        sy += __shfl_xor(sy, off);
        sz += __shfl_xor(sz, off);
    }
    const float cx = sx * (1.0f / 64.0f), cy = sy * (1.0f / 64.0f), cz = sz * (1.0f / 64.0f);
    const float dx = p.x - cx, dy = p.y - cy, dz = p.z - cz;
    float d2 = dx * dx + dy * dy + dz * dz;
#pragma unroll
    for (int off = 32; off; off >>= 1) d2 = fmaxf(d2, __shfl_xor(d2, off));
    if (lane == 0)
        grp[g] = make_float4(cx, cy, cz, sqrtf(d2) * 1.0005f + 1e-6f);
}

// --- h = relu(x @ W + b), x[N,64], W[64,128], h[N,128] ----------------------
__global__ __launch_bounds__(256) void mlp_kernel(
    const float* __restrict__ x, const float* __restrict__ W,
    const float* __restrict__ b, float* __restrict__ h, int N)
{
    __shared__ float ws[64 * 128];
    __shared__ float xs[MLP_ROWS * 65];
    const int t = threadIdx.x;
    const int r0 = blockIdx.x * MLP_ROWS;

    for (int i = t; i < 64 * 128; i += 256) ws[i] = W[i];
    for (int i = t; i < MLP_ROWS * 64; i += 256) {
        const int r = i >> 6, k = i & 63;
        xs[r * 65 + k] = x[r0 * 64 + i];
    }
    __syncthreads();

    const int tx = t & 31, ty = t >> 5;
    const int c0 = tx * 4, rr = ty * 4;
    float acc[4][4];
#pragma unroll
    for (int i = 0; i < 4; ++i)
#pragma unroll
        for (int j = 0; j < 4; ++j) acc[i][j] = 0.0f;

    for (int k = 0; k < 64; ++k) {
        const float4 w4 = *(const float4*)(&ws[k * 128 + c0]);
#pragma unroll
        for (int i = 0; i < 4; ++i) {
            const float xv = xs[(rr + i) * 65 + k];
            acc[i][0] += xv * w4.x;
            acc[i][1] += xv * w4.y;
            acc[i][2] += xv * w4.z;
            acc[i][3] += xv * w4.w;
        }
    }
    const float4 b4 = *(const float4*)(&b[c0]);
#pragma unroll
    for (int i = 0; i < 4; ++i) {
        float4 o;
        o.x = fmaxf(acc[i][0] + b4.x, 0.0f);
        o.y = fmaxf(acc[i][1] + b4.y, 0.0f);
        o.z = fmaxf(acc[i][2] + b4.z, 0.0f);
        o.w = fmaxf(acc[i][3] + b4.w, 0.0f);
        *(float4*)(&h[(size_t)(r0 + rr + i) * 128 + c0]) = o;
    }
}

// --- FPS, LDS-resident state ------------------------------------------------
// slot sg = w*32 + j  <->  sorted group g = j*16 + w  (interleaved balance).
__global__ __launch_bounds__(FPS_T) void fps3_kernel(
    const float4* __restrict__ spts, const float4* __restrict__ grp,
    const float* __restrict__ pos, int* __restrict__ out_idx, int M)
{
    const int t = threadIdx.x;
    const int w = t >> 6;
    const int lane = t & 63;

    __shared__ float mindS[NPTS];                 // 128 KB
    __shared__ unsigned long long gkey[NG];       // 4 KB   (slot-indexed)
    __shared__ float4 gpt[NG];                    // 8 KB   group winner coords (slot)
    __shared__ float4 ballS[NG];                  // 8 KB   group balls (slot)
    __shared__ float4 pickC;                      // current pick coords

    for (int i = t; i < NPTS; i += FPS_T) mindS[i] = __builtin_inff();
    if (t < NG) {
        const int g = ((t & 31) << 4) | (t >> 5);           // slot t -> group g
        ballS[t] = grp[g];
        gkey[t] = (0x7f800000ULL << 32);                    // maxmind=+inf: all touched @s=1
    }
    if (t == 0) {
        out_idx[0] = 0;
        pickC = make_float4(pos[0], pos[1], pos[2], 0.0f);  // orig point 0
    }
    __syncthreads();

    for (int s = 1; s < M; ++s) {
        const float4 pk = pickC;                            // LDS broadcast
        const float lx = pk.x, ly = pk.y, lz = pk.z;

        // bound check: lanes 0..31, slot = w*32 + lane (conflict-free b128)
        bool touched = false;
        if (lane < 32) {
            const int sg = (w << 5) + lane;
            const float4 m4 = ballS[sg];
            const float ddx = lx - m4.x, ddy = ly - m4.y, ddz = lz - m4.z;
            const float dc = sqrtf(ddx * ddx + ddy * ddy + ddz * ddz);
            const float lb = dc - m4.w;
            const float gm = __uint_as_float((unsigned)(gkey[sg] >> 32));
            touched = (lb <= 0.0f) || (lb * lb * 0.9995f < gm);
        }
        unsigned long long mask = __ballot(touched);

        if (mask) {
            int k = __builtin_ctzll(mask);
            mask &= mask - 1;
            float4 p = spts[(((k << 4) | w) << 6) + lane];  // group g = k*16+w
            for (;;) {
                int kn = -1;
                float4 pn = p;
                if (mask) {                                  // depth-2 pipeline
                    kn = __builtin_ctzll(mask);
                    mask &= mask - 1;
                    pn = spts[(((kn << 4) | w) << 6) + lane];
                }
                const int base = (((k << 4) | w) << 6) + lane;
                float md = mindS[base];
                const float dx = p.x - lx;
                const float dy = p.y - ly;
                const float dz = p.z - lz;
                const float d = dx * dx + dy * dy + dz * dz;
                md = fminf(md, d);
                mindS[base] = md;
                const unsigned oi = (unsigned)__float_as_int(p.w);
                unsigned long long key =
                    ((unsigned long long)__float_as_uint(md) << 32) | (0xffffffffu - oi);
                const unsigned long long mykey = key;
#pragma unroll
                for (int off = 32; off; off >>= 1) {
                    const unsigned long long o = __shfl_xor(key, off);
                    if (o > key) key = o;
                }
                const int sg = (w << 5) + k;
                if (lane == 0) gkey[sg] = key;
                if (mykey == key)                            // unique: key has unique idx
                    gpt[sg] = make_float4(p.x, p.y, p.z, 0.0f);
                if (kn < 0) break;
                k = kn;
                p = pn;
            }
        }
        __syncthreads();                                     // all gkey/gpt visible

        if (w == 0) {
            unsigned long long best = 0;
            int bslot = 0;
#pragma unroll
            for (int j = 0; j < NG / 64; ++j) {
                const unsigned long long v = gkey[lane + (j << 6)];
                if (v > best) { best = v; bslot = lane + (j << 6); }
            }
#pragma unroll
            for (int off = 32; off; off >>= 1) {
                const unsigned long long ov = __shfl_xor(best, off);
                const int obs = __shfl_xor(bslot, off);
                if (ov > best) { best = ov; bslot = obs; }
            }
            if (lane == 0) {
                out_idx[s] = (int)(0xffffffffu - (unsigned)(best & 0xffffffffu));
                pickC = gpt[bslot];
            }
        }
        __syncthreads();                                     // pickC ready
    }
}

// --- KNN (exact top-16 by (d, idx)) + gather-max over h + sub outputs -------
__global__ __launch_bounds__(256) void knn_kernel(
    const float* __restrict__ posx, const float* __restrict__ posy,
    const float* __restrict__ posz, const int* __restrict__ idx,
    const float* __restrict__ h, const float* __restrict__ pos,
    const int* __restrict__ batch, float* __restrict__ out,
    float* __restrict__ out_subpos, int* __restrict__ out_subbatch,
    int N, int M, int Cout)
{
    const int q = (int)((blockIdx.x * (unsigned)blockDim.x + threadIdx.x) >> 6);
    const int lane = threadIdx.x & 63;
    if (q >= M) return;

    const int qi = idx[q];
    const float qx = posx[qi], qy = posy[qi], qz = posz[qi];

    float d16[KNN_K]; int i16[KNN_K];
#pragma unroll
    for (int k = 0; k < KNN_K; ++k) { d16[k] = __builtin_inff(); i16[k] = 0x7fffffff; }
    float lmax = __builtin_inff();
    int lslot = 0;
    float T = __builtin_inff();

    const int iters = N >> 6;
    for (int c = 0; c < iters; ++c) {
        const int p = c * 64 + lane;
        const float dx = posx[p] - qx;
        const float dy = posy[p] - qy;
        const float dz = posz[p] - qz;
        const float d = dx * dx + dy * dy + dz * dz;
        if (d < T && d < lmax) {
            d16[lslot] = d; i16[lslot] = p;
            lmax = d16[0]; lslot = 0;
#pragma unroll
            for (int k = 1; k < KNN_K; ++k)
                if (d16[k] > lmax) { lmax = d16[k]; lslot = k; }
        }
        if ((c & 31) == 31) {
            float tt = lmax;
#pragma unroll
            for (int off = 32; off > 0; off >>= 1)
                tt = fminf(tt, __shfl_xor(tt, off));
            T = tt;
        }
    }

    int nbr[KNN_K];
#pragma unroll
    for (int r = 0; r < KNN_K; ++r) {
        float lv = d16[0]; int ls = 0;
#pragma unroll
        for (int k = 1; k < KNN_K; ++k)
            if (d16[k] < lv || (d16[k] == lv && i16[k] < i16[ls])) { lv = d16[k]; ls = k; }
        float mv = lv; int mi = i16[ls];
#pragma unroll
        for (int off = 32; off > 0; off >>= 1) {
            const float ov = __shfl_xor(mv, off);
            const int   oi = __shfl_xor(mi, off);
            if (ov < mv || (ov == mv && oi < mi)) { mv = ov; mi = oi; }
        }
        if (i16[ls] == mi) d16[ls] = __builtin_inff();
        nbr[r] = mi;
    }

    for (int c = lane; c < Cout; c += 64) {
        float a = -__builtin_inff();
#pragma unroll
        for (int r = 0; r < KNN_K; ++r)
            a = fmaxf(a, h[(size_t)nbr[r] * Cout + c]);
        out[(size_t)q * Cout + c] = a;
    }
    if (lane < 3) out_subpos[q * 3 + lane] = pos[qi * 3 + lane];
    if (lane == 3) out_subbatch[q] = batch[qi];
}

// ---------------------------------------------------------------------------
extern "C" void kernel_launch(void* const* d_in, const int* in_sizes, int n_in,
                              void* d_out, int out_size, void* d_ws, size_t ws_size,
                              hipStream_t stream)
{
    const float* x     = (const float*)d_in[0];
    const float* pos   = (const float*)d_in[1];
    const int*   batch = (const int*)d_in[2];
    const float* W     = (const float*)d_in[3];
    const float* b     = (const float*)d_in[4];

    const int N    = in_sizes[2];       // 32768
    const int Cout = in_sizes[4];       // 128
    const int M    = N / 4;             // 8192
    const int ngroups = N / 64;         // 512 == NG

    // ws layout: spts f4[N] | grp f4[NG] | posx,posy,posz [N] | hist [NCELL]
    //          | idx [M] | h [N*Cout]
    float4* spts = (float4*)d_ws;
    float4* grp  = spts + N;
    float*  posx = (float*)(grp + NG);
    float*  posy = posx + N;
    float*  posz = posy + N;
    int*    hist = (int*)(posz + N);
    int*    idx  = hist + NCELL;
    float*  h    = (float*)(idx + M);

    float* out          = (float*)d_out;
    float* out_subpos   = out + (size_t)M * Cout;
    int*   out_subbatch = (int*)(out_subpos + (size_t)M * 3);

    prep_kernel<<<(N + 255) / 256, 256, 0, stream>>>(pos, posx, posy, posz, N);
    zero_kernel<<<NCELL / 256, 256, 0, stream>>>(hist);
    hist_kernel<<<(N + 255) / 256, 256, 0, stream>>>(pos, hist, N);
    scan_kernel<<<1, 1024, 0, stream>>>(hist);
    scatter_kernel<<<(N + 255) / 256, 256, 0, stream>>>(pos, hist, spts, N);
    grpmeta_kernel<<<(ngroups * 64 + 255) / 256, 256, 0, stream>>>(spts, grp, ngroups);
    mlp_kernel<<<N / MLP_ROWS, 256, 0, stream>>>(x, W, b, h, N);
    fps3_kernel<<<1, FPS_T, 0, stream>>>(spts, grp, pos, idx, M);
    knn_kernel<<<(M * 64) / 256, 256, 0, stream>>>(posx, posy, posz, idx, h, pos, batch,
                                                   out, out_subpos, out_subbatch, N, M, Cout);
}